// Round 2
// baseline (283.014 us; speedup 1.0000x reference)
//
#include <hip/hip_runtime.h>
#include <hip/hip_bf16.h>

// Correctness contract (verified R6-R8 of prior session, absmax=0):
//   xc   = sequential __fmaf_rn chain over d=0..63 ascending
//   x2,c2= numpy pairwise scalar 8-accumulator scheme
//   dist = fl(fl(x2 - 2*xc) + c2), argmin first-occurrence
// Fast pass: split-bf16 MFMA on (-2c) with C2-initialized accumulator;
// |fast - exact| << MARGIN. Near-ties (gap<=MARGIN) -> bit-exact rescan.
//
// R-this-round (write-path theory):
//  * iout was [token][16m] written 4B-at-a-time by 16 different blocks on
//    different XCDs -> partial-line RMW, ~67MB excess HBM writes (measured
//    WRITE_SIZE 135MB vs 68MB ideal). Indices now go to ws in [m][token]
//    layout (block-exclusive full lines); tiny transpose kernel emits the
//    [token][16] output with one full 64B line per thread.
//  * 1-D grid with m = rank&15: XCD (rank%8) only touches m in {x, x+8} ->
//    bpack/cb L2 footprint per XCD 4MB->512KB (saves ~24MB HBM fetch).
//  Compute structure identical to R1 (isolates the memory-path change).
#pragma clang fp contract(off)

#define NSUB 16
#define CBK  1024
#define SDIM 64
#define EMB  1024
#define NTOK 16384
#define TOKB 128
#define MARGIN 5e-3f

typedef __attribute__((ext_vector_type(8))) short bf16x8;
typedef __attribute__((ext_vector_type(4))) float f32x4;

__device__ __forceinline__ float fmul(float a, float b) { return __fmul_rn(a, b); }
__device__ __forceinline__ float fadd(float a, float b) { return __fadd_rn(a, b); }
__device__ __forceinline__ float fsub(float a, float b) { return __fsub_rn(a, b); }

// numpy pairwise replica (scalar 8-accumulator, n=64), contiguous.
__device__ __forceinline__ float np_sq64(const float* v) {
    float r[8];
    #pragma unroll
    for (int j = 0; j < 8; ++j) r[j] = fmul(v[j], v[j]);
    #pragma unroll
    for (int b = 1; b < 8; ++b) {
        #pragma unroll
        for (int j = 0; j < 8; ++j)
            r[j] = fadd(r[j], fmul(v[b * 8 + j], v[b * 8 + j]));
    }
    return fadd(fadd(fadd(r[0], r[1]), fadd(r[2], r[3])),
                fadd(fadd(r[4], r[5]), fadd(r[6], r[7])));
}

__device__ __forceinline__ void split_bf16(float v, short& hi, short& lo) {
    __hip_bfloat16 h = __float2bfloat16(v);
    float hf = __bfloat162float(h);
    __hip_bfloat16 e = __float2bfloat16(__fsub_rn(v, hf));
    hi = *(short*)&h;
    lo = *(short*)&e;
}

// async global->LDS, 16B per lane. LDS dest must be uniform-base + lane*16,
// which our linear bpack tile layout satisfies exactly.
typedef const __attribute__((address_space(1))) unsigned int gu32;
typedef __attribute__((address_space(3))) unsigned int lu32;
__device__ __forceinline__ void stage16(const void* g, void* l) {
    __builtin_amdgcn_global_load_lds((gu32*)g, (lu32*)l, 16, 0, 0);
}

// ---- prep: pack (-2*codebook) into MFMA B-fragment layout (bf16 hi/lo) + C2 ----
// bpack layout: [m][tc=64][c=2][part=2][lane=64][j=8] bf16  (4 MB) -- unchanged.
__global__ __launch_bounds__(256)
void prep_kernel(const float* __restrict__ cb,
                 unsigned short* __restrict__ bpack,
                 float* __restrict__ c2g)
{
    const int bx = blockIdx.x;   // 0..31
    const int m  = blockIdx.y;   // 0..15
    const int t  = threadIdx.x;
    const int w  = t >> 6, l = t & 63;
    const int tc = bx * 2 + (w & 1);           // tile-col 0..63
    const int c  = w >> 1;                     // c-half 0..1
    const int cw = tc * 16 + (l & 15);
    const int dq = (l >> 4) * 8;

    {
        const float* src = cb + ((size_t)m * CBK + cw) * SDIM + c * 32 + dq;
        bf16x8 hv, lv;
        #pragma unroll
        for (int j = 0; j < 8; ++j) {
            short h, e; split_bf16(-2.0f * src[j], h, e);  // -2x exact in fp32
            hv[j] = h; lv[j] = e;
        }
        size_t base = (((size_t)(m * 64 + tc) * 2 + c) * 2) * 512 + (size_t)l * 8;
        *(bf16x8*)(bpack + base)       = hv;   // 16B vector stores, coalesced
        *(bf16x8*)(bpack + base + 512) = lv;
    }
    if (t < 32) {
        const int row = bx * 32 + t;
        c2g[m * CBK + row] = np_sq64(cb + ((size_t)m * CBK + row) * SDIM);
    }
}

// ---- transpose: ws indices [m][NTOK] -> iout [NTOK][16], full-line writes ----
__global__ __launch_bounds__(256)
void idx_transpose_kernel(const float* __restrict__ iws,
                          float* __restrict__ iout)
{
    const int tok = blockIdx.x * 256 + threadIdx.x;
    float v[NSUB];
    #pragma unroll
    for (int m = 0; m < NSUB; ++m)
        v[m] = iws[(size_t)m * NTOK + tok];      // coalesced per-m reads
    float* dst = iout + (size_t)tok * NSUB;      // 64B line per thread
    #pragma unroll
    for (int c = 0; c < 4; ++c)
        *(f32x4*)(dst + c * 4) = *(f32x4*)(v + c * 4);
}

// ---- main: MFMA fast pass, B staged via LDS double-buffer (4 tiles/phase) ----
__global__ __launch_bounds__(256, 4)
void pq_mfma_kernel(const float* __restrict__ emb,
                    const float* __restrict__ cb,
                    const unsigned short* __restrict__ bpack,
                    const float* __restrict__ c2g,
                    float* __restrict__ qout,
                    float* __restrict__ iws)
{
    __shared__ __align__(16) unsigned short bs[2][4 * 2048];  // 2 x 16KB B stage
    __shared__ float C2s[CBK];              // 4 KB replica ||c||^2
    __shared__ float red_v[256];
    __shared__ int   red_k[256];
    __shared__ int   bestk_s[TOKB];
    __shared__ int   flag_s[TOKB];
    __shared__ int   cnt_s;

    // XCD-aware decomposition: XCD (rank%8) only sees m in {rank%8, rank%8+8}
    const int rank = blockIdx.x;
    const int m    = rank & 15;
    const int tok0 = (rank >> 4) * TOKB;

    const int t = threadIdx.x, w = t >> 6, l = t & 63;
    const int ln15 = l & 15, q = l >> 4;

    if (t == 0) cnt_s = 0;
    *(f32x4*)(C2s + t * 4) = *(const f32x4*)(c2g + m * CBK + t * 4);

    const unsigned short* gB = bpack + (size_t)m * 64 * 2048;  // 256KB slice

    // stage phase 0 (tiles 0..3): thread t covers bytes [t*16, t*16+16) of each tile
    {
        const unsigned short* src = gB + t * 8;
        #pragma unroll
        for (int j = 0; j < 4; ++j)
            stage16(src + j * 2048, &bs[0][j * 2048 + t * 8]);
    }

    // x fragments (A-operand: row=lane&15, k=(lane>>4)*8+j), split hi/lo
    bf16x8 xh[2][2], xl[2][2];
    #pragma unroll
    for (int r = 0; r < 2; ++r) {
        const int tok = tok0 + w * 32 + r * 16 + ln15;
        #pragma unroll
        for (int c = 0; c < 2; ++c) {
            const float* src = emb + (size_t)tok * EMB + m * SDIM + c * 32 + q * 8;
            float4 v0 = *(const float4*)(src);
            float4 v1 = *(const float4*)(src + 4);
            float vv[8] = {v0.x,v0.y,v0.z,v0.w,v1.x,v1.y,v1.z,v1.w};
            #pragma unroll
            for (int j = 0; j < 8; ++j) {
                short h, e; split_bf16(vv[j], h, e);
                xh[r][c][j] = h; xl[r][c][j] = e;
            }
        }
    }

    float v1t[2][4], v2t[2][4]; int k1t[2][4];
    #pragma unroll
    for (int r = 0; r < 2; ++r)
        #pragma unroll
        for (int g = 0; g < 4; ++g) { v1t[r][g] = 3.4e38f; v2t[r][g] = 3.4e38f; k1t[r][g] = 0; }

    __syncthreads();   // C2s ready + phase-0 stage complete (vmcnt drained by barrier)

#define COMPUTE_TILE(B0, B1, B2, B3, TC)                                        \
    {                                                                           \
        const int kk = (TC) * 16 + ln15;                                        \
        const float c2v = C2s[kk];                                              \
        _Pragma("unroll")                                                       \
        for (int r = 0; r < 2; ++r) {                                           \
            f32x4 acc = {c2v, c2v, c2v, c2v};                                   \
            acc = __builtin_amdgcn_mfma_f32_16x16x32_bf16(xh[r][0], B0, acc, 0, 0, 0); \
            acc = __builtin_amdgcn_mfma_f32_16x16x32_bf16(xh[r][1], B2, acc, 0, 0, 0); \
            acc = __builtin_amdgcn_mfma_f32_16x16x32_bf16(xl[r][0], B0, acc, 0, 0, 0); \
            acc = __builtin_amdgcn_mfma_f32_16x16x32_bf16(xl[r][1], B2, acc, 0, 0, 0); \
            acc = __builtin_amdgcn_mfma_f32_16x16x32_bf16(xh[r][0], B1, acc, 0, 0, 0); \
            acc = __builtin_amdgcn_mfma_f32_16x16x32_bf16(xh[r][1], B3, acc, 0, 0, 0); \
            _Pragma("unroll")                                                   \
            for (int g = 0; g < 4; ++g) {                                       \
                float s = acc[g];                                               \
                v2t[r][g] = fminf(v2t[r][g], fmaxf(s, v1t[r][g]));              \
                bool lt = s < v1t[r][g];                                        \
                v1t[r][g] = lt ? s : v1t[r][g];                                 \
                k1t[r][g] = lt ? kk : k1t[r][g];                                \
            }                                                                   \
        }                                                                       \
    }

    // 16 phases x 4 tiles; stage next phase while computing current.
    for (int ph = 0; ph < 16; ++ph) {
        const int buf = ph & 1;
        if (ph < 15) {
            const unsigned short* src = gB + (size_t)(ph + 1) * 8192 + t * 8;
            #pragma unroll
            for (int j = 0; j < 4; ++j)
                stage16(src + j * 2048, &bs[buf ^ 1][j * 2048 + t * 8]);
        }
        #pragma unroll
        for (int j = 0; j < 4; ++j) {
            const int tc = ph * 4 + j;
            const unsigned short* bp = &bs[buf][j * 2048 + l * 8];
            bf16x8 B0 = *(const bf16x8*)(bp);
            bf16x8 B1 = *(const bf16x8*)(bp + 512);
            bf16x8 B2 = *(const bf16x8*)(bp + 1024);
            bf16x8 B3 = *(const bf16x8*)(bp + 1536);
            COMPUTE_TILE(B0, B1, B2, B3, tc)
        }
        __syncthreads();
    }
#undef COMPUTE_TILE

    // merge top-2 across the 16 lanes sharing each token (C/D row = q*4+g)
    #pragma unroll
    for (int r = 0; r < 2; ++r) {
        #pragma unroll
        for (int g = 0; g < 4; ++g) {
            float v1 = v1t[r][g], v2 = v2t[r][g]; int k1 = k1t[r][g];
            #pragma unroll
            for (int mask = 1; mask < 16; mask <<= 1) {
                float ov1 = __shfl_xor(v1, mask);
                float ov2 = __shfl_xor(v2, mask);
                int   ok1 = __shfl_xor(k1, mask);
                if (ov1 < v1 || (ov1 == v1 && ok1 < k1)) {
                    v2 = fminf(v1, ov2);
                    v1 = ov1; k1 = ok1;
                } else {
                    v2 = fminf(v2, ov1);
                }
            }
            if (ln15 == 0) {
                const int token = w * 32 + r * 16 + q * 4 + g;
                if (v2 - v1 <= MARGIN) {
                    int slot = atomicAdd(&cnt_s, 1);
                    flag_s[slot] = token;
                } else {
                    bestk_s[token] = k1;
                    // [m][token] ws layout: block-exclusive 512B segment, full lines
                    iws[(size_t)m * NTOK + tok0 + token] = (float)k1;
                }
            }
        }
    }
    __syncthreads();

    // ---- pass 2: bit-exact chain rescan for flagged tokens ----
    const int nflag = cnt_s;
    for (int f = 0; f < nflag; ++f) {
        const int token = flag_s[f];
        const float* xrow = emb + (size_t)(tok0 + token) * EMB + m * SDIM;
        const float x2v = np_sq64(xrow);          // broadcast reads, L1-hot
        float bs_ = 3.4e38f; int bk = CBK;
        #pragma unroll
        for (int rr = 0; rr < 4; ++rr) {
            const int k = t + 256 * rr;           // ascending per thread
            const float* crow = cb + ((size_t)m * CBK + k) * SDIM;
            float acc = 0.f;
            #pragma unroll
            for (int i = 0; i < 16; ++i) {
                float4 c4 = *(const float4*)(crow + 4 * i);
                float4 x4 = *(const float4*)(xrow + 4 * i);
                acc = __fmaf_rn(x4.x, c4.x, acc);
                acc = __fmaf_rn(x4.y, c4.y, acc);
                acc = __fmaf_rn(x4.z, c4.z, acc);
                acc = __fmaf_rn(x4.w, c4.w, acc);
            }
            const float dist = fadd(fsub(x2v, fmul(2.f, acc)), C2s[k]);
            if (dist < bs_) { bs_ = dist; bk = k; }
        }
        red_v[t] = bs_; red_k[t] = bk;
        __syncthreads();
        for (int off = 128; off > 0; off >>= 1) {
            if (t < off) {
                float o = red_v[t + off]; int ok = red_k[t + off];
                if (o < red_v[t] || (o == red_v[t] && ok < red_k[t])) {
                    red_v[t] = o; red_k[t] = ok;
                }
            }
            __syncthreads();
        }
        if (t == 0) {
            bestk_s[token] = red_k[0];
            iws[(size_t)m * NTOK + tok0 + token] = (float)red_k[0];
        }
        __syncthreads();
    }

    // ---- gather winning codewords ----
    {
        const int tok = t >> 1, d0 = (t & 1) * 32;
        const int bk  = bestk_s[tok];
        const float* src = cb + ((size_t)m * CBK + bk) * SDIM + d0;
        float* dst = qout + (size_t)(tok0 + tok) * EMB + m * SDIM + d0;
        #pragma unroll
        for (int i = 0; i < 8; ++i)
            *(float4*)(dst + 4 * i) = *(const float4*)(src + 4 * i);
    }
}

extern "C" void kernel_launch(void* const* d_in, const int* in_sizes, int n_in,
                              void* d_out, int out_size, void* d_ws, size_t ws_size,
                              hipStream_t stream) {
    const float* emb = (const float*)d_in[0];   // [8,2048,1024] f32
    const float* cb  = (const float*)d_in[1];   // [16,1024,64] f32
    float* qout = (float*)d_out;                              // [N, EMB] f32
    float* iout = (float*)d_out + (size_t)NTOK * EMB;         // [N, 16] as f32

    unsigned short* bpack = (unsigned short*)d_ws;            // 4 MB
    float* c2g = (float*)((char*)d_ws + 4u * 1024u * 1024u);  // 64 KB
    float* iws = (float*)((char*)d_ws + 4u * 1024u * 1024u + 64u * 1024u); // 1 MB

    prep_kernel<<<dim3(32, 16), 256, 0, stream>>>(cb, bpack, c2g);
    pq_mfma_kernel<<<dim3(NTOK / TOKB * NSUB), 256, 0, stream>>>(
        emb, cb, bpack, c2g, qout, iws);
    idx_transpose_kernel<<<dim3(NTOK / 256), 256, 0, stream>>>(iws, iout);
}

// Round 3
// 253.795 us; speedup vs baseline: 1.1151x; 1.1151x over previous
//
#include <hip/hip_runtime.h>
#include <hip/hip_bf16.h>

// Correctness contract (verified R6-R8 of prior session, absmax=0):
//   xc   = sequential __fmaf_rn chain over d=0..63 ascending
//   x2,c2= numpy pairwise scalar 8-accumulator scheme
//   dist = fl(fl(x2 - 2*xc) + c2), argmin first-occurrence
// Fast pass: split-bf16 MFMA on (-2c) with C2-initialized accumulator;
// |fast - exact| <= eps << MARGIN. Near-ties (gap<=MARGIN) -> exact rescan.
//
// R-this-round (pass-2 work reduction):
//   VALU accounting showed pass-2 (full 1024-codeword block-wide rescan per
//   flagged token, ~20% flag rate) was ~50% of kernel time. Replaced by:
//   (a) MFMA fast re-pass over flagged tokens only (16/group, 1 wave/group,
//       barrier-free) collecting candidate masks {k: fast <= v1_run+MARGIN}
//       -- a guaranteed superset of {k: fast <= v1_final+MARGIN}, which
//       contains the exact argmin whenever MARGIN >= 2*eps (same bound the
//       original scheme relied on);
//   (b) bit-exact chain evaluation of only those ~1-3 candidates/token,
//       (val,k)-lexicographic shfl reduce. Main loop byte-identical to R2.
#pragma clang fp contract(off)

#define NSUB 16
#define CBK  1024
#define SDIM 64
#define EMB  1024
#define NTOK 16384
#define TOKB 128
#define MARGIN 5e-3f

typedef __attribute__((ext_vector_type(8))) short bf16x8;
typedef __attribute__((ext_vector_type(4))) float f32x4;

__device__ __forceinline__ float fmul(float a, float b) { return __fmul_rn(a, b); }
__device__ __forceinline__ float fadd(float a, float b) { return __fadd_rn(a, b); }
__device__ __forceinline__ float fsub(float a, float b) { return __fsub_rn(a, b); }

// numpy pairwise replica (scalar 8-accumulator, n=64), contiguous.
__device__ __forceinline__ float np_sq64(const float* v) {
    float r[8];
    #pragma unroll
    for (int j = 0; j < 8; ++j) r[j] = fmul(v[j], v[j]);
    #pragma unroll
    for (int b = 1; b < 8; ++b) {
        #pragma unroll
        for (int j = 0; j < 8; ++j)
            r[j] = fadd(r[j], fmul(v[b * 8 + j], v[b * 8 + j]));
    }
    return fadd(fadd(fadd(r[0], r[1]), fadd(r[2], r[3])),
                fadd(fadd(r[4], r[5]), fadd(r[6], r[7])));
}

__device__ __forceinline__ void split_bf16(float v, short& hi, short& lo) {
    __hip_bfloat16 h = __float2bfloat16(v);
    float hf = __bfloat162float(h);
    __hip_bfloat16 e = __float2bfloat16(__fsub_rn(v, hf));
    hi = *(short*)&h;
    lo = *(short*)&e;
}

// async global->LDS, 16B per lane. LDS dest must be uniform-base + lane*16,
// which our linear bpack tile layout satisfies exactly.
typedef const __attribute__((address_space(1))) unsigned int gu32;
typedef __attribute__((address_space(3))) unsigned int lu32;
__device__ __forceinline__ void stage16(const void* g, void* l) {
    __builtin_amdgcn_global_load_lds((gu32*)g, (lu32*)l, 16, 0, 0);
}

// ---- prep: pack (-2*codebook) into MFMA B-fragment layout (bf16 hi/lo) + C2 ----
// bpack layout: [m][tc=64][c=2][part=2][lane=64][j=8] bf16  (4 MB) -- unchanged.
__global__ __launch_bounds__(256)
void prep_kernel(const float* __restrict__ cb,
                 unsigned short* __restrict__ bpack,
                 float* __restrict__ c2g)
{
    const int bx = blockIdx.x;   // 0..31
    const int m  = blockIdx.y;   // 0..15
    const int t  = threadIdx.x;
    const int w  = t >> 6, l = t & 63;
    const int tc = bx * 2 + (w & 1);           // tile-col 0..63
    const int c  = w >> 1;                     // c-half 0..1
    const int cw = tc * 16 + (l & 15);
    const int dq = (l >> 4) * 8;

    {
        const float* src = cb + ((size_t)m * CBK + cw) * SDIM + c * 32 + dq;
        bf16x8 hv, lv;
        #pragma unroll
        for (int j = 0; j < 8; ++j) {
            short h, e; split_bf16(-2.0f * src[j], h, e);  // -2x exact in fp32
            hv[j] = h; lv[j] = e;
        }
        size_t base = (((size_t)(m * 64 + tc) * 2 + c) * 2) * 512 + (size_t)l * 8;
        *(bf16x8*)(bpack + base)       = hv;   // 16B vector stores, coalesced
        *(bf16x8*)(bpack + base + 512) = lv;
    }
    if (t < 32) {
        const int row = bx * 32 + t;
        c2g[m * CBK + row] = np_sq64(cb + ((size_t)m * CBK + row) * SDIM);
    }
}

// ---- transpose: ws indices [m][NTOK] -> iout [NTOK][16], full-line writes ----
__global__ __launch_bounds__(256)
void idx_transpose_kernel(const float* __restrict__ iws,
                          float* __restrict__ iout)
{
    const int tok = blockIdx.x * 256 + threadIdx.x;
    float v[NSUB];
    #pragma unroll
    for (int m = 0; m < NSUB; ++m)
        v[m] = iws[(size_t)m * NTOK + tok];      // coalesced per-m reads
    float* dst = iout + (size_t)tok * NSUB;      // 64B line per thread
    #pragma unroll
    for (int c = 0; c < 4; ++c)
        *(f32x4*)(dst + c * 4) = *(f32x4*)(v + c * 4);
}

// ---- main: MFMA fast pass + candidate-set exact rescan ----
__global__ __launch_bounds__(256, 4)
void pq_mfma_kernel(const float* __restrict__ emb,
                    const float* __restrict__ cb,
                    const unsigned short* __restrict__ bpack,
                    const float* __restrict__ c2g,
                    float* __restrict__ qout,
                    float* __restrict__ iws)
{
    __shared__ __align__(16) unsigned short bs[2][4 * 2048];  // 2 x 16KB B stage
    __shared__ float C2s[CBK];              // 4 KB replica ||c||^2
    __shared__ int   bestk_s[TOKB];
    __shared__ int   flag_s[TOKB];
    __shared__ int   cnt_s;

    // XCD-aware decomposition: XCD (rank%8) only sees m in {rank%8, rank%8+8}
    const int rank = blockIdx.x;
    const int m    = rank & 15;
    const int tok0 = (rank >> 4) * TOKB;

    const int t = threadIdx.x, w = t >> 6, l = t & 63;
    const int ln15 = l & 15, q = l >> 4;

    if (t == 0) cnt_s = 0;
    *(f32x4*)(C2s + t * 4) = *(const f32x4*)(c2g + m * CBK + t * 4);

    const unsigned short* gB = bpack + (size_t)m * 64 * 2048;  // 256KB slice

    // stage phase 0 (tiles 0..3): thread t covers bytes [t*16, t*16+16) of each tile
    {
        const unsigned short* src = gB + t * 8;
        #pragma unroll
        for (int j = 0; j < 4; ++j)
            stage16(src + j * 2048, &bs[0][j * 2048 + t * 8]);
    }

    // x fragments (A-operand: row=lane&15, k=(lane>>4)*8+j), split hi/lo
    bf16x8 xh[2][2], xl[2][2];
    #pragma unroll
    for (int r = 0; r < 2; ++r) {
        const int tok = tok0 + w * 32 + r * 16 + ln15;
        #pragma unroll
        for (int c = 0; c < 2; ++c) {
            const float* src = emb + (size_t)tok * EMB + m * SDIM + c * 32 + q * 8;
            float4 v0 = *(const float4*)(src);
            float4 v1 = *(const float4*)(src + 4);
            float vv[8] = {v0.x,v0.y,v0.z,v0.w,v1.x,v1.y,v1.z,v1.w};
            #pragma unroll
            for (int j = 0; j < 8; ++j) {
                short h, e; split_bf16(vv[j], h, e);
                xh[r][c][j] = h; xl[r][c][j] = e;
            }
        }
    }

    float v1t[2][4], v2t[2][4]; int k1t[2][4];
    #pragma unroll
    for (int r = 0; r < 2; ++r)
        #pragma unroll
        for (int g = 0; g < 4; ++g) { v1t[r][g] = 3.4e38f; v2t[r][g] = 3.4e38f; k1t[r][g] = 0; }

    __syncthreads();   // C2s ready + phase-0 stage complete (vmcnt drained by barrier)

#define COMPUTE_TILE(B0, B1, B2, B3, TC)                                        \
    {                                                                           \
        const int kk = (TC) * 16 + ln15;                                        \
        const float c2v = C2s[kk];                                              \
        _Pragma("unroll")                                                       \
        for (int r = 0; r < 2; ++r) {                                           \
            f32x4 acc = {c2v, c2v, c2v, c2v};                                   \
            acc = __builtin_amdgcn_mfma_f32_16x16x32_bf16(xh[r][0], B0, acc, 0, 0, 0); \
            acc = __builtin_amdgcn_mfma_f32_16x16x32_bf16(xh[r][1], B2, acc, 0, 0, 0); \
            acc = __builtin_amdgcn_mfma_f32_16x16x32_bf16(xl[r][0], B0, acc, 0, 0, 0); \
            acc = __builtin_amdgcn_mfma_f32_16x16x32_bf16(xl[r][1], B2, acc, 0, 0, 0); \
            acc = __builtin_amdgcn_mfma_f32_16x16x32_bf16(xh[r][0], B1, acc, 0, 0, 0); \
            acc = __builtin_amdgcn_mfma_f32_16x16x32_bf16(xh[r][1], B3, acc, 0, 0, 0); \
            _Pragma("unroll")                                                   \
            for (int g = 0; g < 4; ++g) {                                       \
                float s = acc[g];                                               \
                v2t[r][g] = fminf(v2t[r][g], fmaxf(s, v1t[r][g]));              \
                bool lt = s < v1t[r][g];                                        \
                v1t[r][g] = lt ? s : v1t[r][g];                                 \
                k1t[r][g] = lt ? kk : k1t[r][g];                                \
            }                                                                   \
        }                                                                       \
    }

    // 16 phases x 4 tiles; stage next phase while computing current.
    for (int ph = 0; ph < 16; ++ph) {
        const int buf = ph & 1;
        if (ph < 15) {
            const unsigned short* src = gB + (size_t)(ph + 1) * 8192 + t * 8;
            #pragma unroll
            for (int j = 0; j < 4; ++j)
                stage16(src + j * 2048, &bs[buf ^ 1][j * 2048 + t * 8]);
        }
        #pragma unroll
        for (int j = 0; j < 4; ++j) {
            const int tc = ph * 4 + j;
            const unsigned short* bp = &bs[buf][j * 2048 + l * 8];
            bf16x8 B0 = *(const bf16x8*)(bp);
            bf16x8 B1 = *(const bf16x8*)(bp + 512);
            bf16x8 B2 = *(const bf16x8*)(bp + 1024);
            bf16x8 B3 = *(const bf16x8*)(bp + 1536);
            COMPUTE_TILE(B0, B1, B2, B3, tc)
        }
        __syncthreads();
    }
#undef COMPUTE_TILE

    // merge top-2 across the 16 lanes sharing each token (C/D row = q*4+g)
    #pragma unroll
    for (int r = 0; r < 2; ++r) {
        #pragma unroll
        for (int g = 0; g < 4; ++g) {
            float v1 = v1t[r][g], v2 = v2t[r][g]; int k1 = k1t[r][g];
            #pragma unroll
            for (int mask = 1; mask < 16; mask <<= 1) {
                float ov1 = __shfl_xor(v1, mask);
                float ov2 = __shfl_xor(v2, mask);
                int   ok1 = __shfl_xor(k1, mask);
                if (ov1 < v1 || (ov1 == v1 && ok1 < k1)) {
                    v2 = fminf(v1, ov2);
                    v1 = ov1; k1 = ok1;
                } else {
                    v2 = fminf(v2, ov1);
                }
            }
            if (ln15 == 0) {
                const int token = w * 32 + r * 16 + q * 4 + g;
                if (v2 - v1 <= MARGIN) {
                    int slot = atomicAdd(&cnt_s, 1);
                    flag_s[slot] = token;
                } else {
                    bestk_s[token] = k1;
                    iws[(size_t)m * NTOK + tok0 + token] = (float)k1;
                }
            }
        }
    }
    __syncthreads();

    // ---- pass 2: candidate-set rescan, one wave per 16 flagged tokens ----
    const int nflag = cnt_s;
    for (int g0 = w * 16; g0 < nflag; g0 += 64) {
        // A fragments for this group's tokens (load-mapping: row = ln15)
        const int slotL = g0 + ln15;
        const int tokL  = flag_s[slotL < nflag ? slotL : g0];
        bf16x8 fxh[2], fxl[2];
        #pragma unroll
        for (int c = 0; c < 2; ++c) {
            const float* src = emb + (size_t)(tok0 + tokL) * EMB + m * SDIM + c * 32 + q * 8;
            float4 v0 = *(const float4*)(src);
            float4 v1 = *(const float4*)(src + 4);
            float vv[8] = {v0.x,v0.y,v0.z,v0.w,v1.x,v1.y,v1.z,v1.w};
            #pragma unroll
            for (int j = 0; j < 8; ++j) {
                short h, e; split_bf16(vv[j], h, e);
                fxh[c][j] = h; fxl[c][j] = e;
            }
        }

        // fast re-pass: collect candidate masks {k : s <= v1_run + MARGIN}
        unsigned long long cmask[4] = {0ull, 0ull, 0ull, 0ull};
        float v1r[4] = {3.4e38f, 3.4e38f, 3.4e38f, 3.4e38f};
        const unsigned short* bp0 = gB + (size_t)l * 8;
        bf16x8 Bc0 = *(const bf16x8*)(bp0);
        bf16x8 Bc1 = *(const bf16x8*)(bp0 + 512);
        bf16x8 Bc2 = *(const bf16x8*)(bp0 + 1024);
        bf16x8 Bc3 = *(const bf16x8*)(bp0 + 1536);
        #pragma unroll 2
        for (int tc = 0; tc < 64; ++tc) {
            bf16x8 Bn0, Bn1, Bn2, Bn3;
            if (tc < 63) {
                const unsigned short* bpn = gB + (size_t)(tc + 1) * 2048 + (size_t)l * 8;
                Bn0 = *(const bf16x8*)(bpn);
                Bn1 = *(const bf16x8*)(bpn + 512);
                Bn2 = *(const bf16x8*)(bpn + 1024);
                Bn3 = *(const bf16x8*)(bpn + 1536);
            }
            const int kk = tc * 16 + ln15;
            const float c2v = C2s[kk];
            f32x4 acc = {c2v, c2v, c2v, c2v};
            acc = __builtin_amdgcn_mfma_f32_16x16x32_bf16(fxh[0], Bc0, acc, 0, 0, 0);
            acc = __builtin_amdgcn_mfma_f32_16x16x32_bf16(fxh[1], Bc2, acc, 0, 0, 0);
            acc = __builtin_amdgcn_mfma_f32_16x16x32_bf16(fxl[0], Bc0, acc, 0, 0, 0);
            acc = __builtin_amdgcn_mfma_f32_16x16x32_bf16(fxl[1], Bc2, acc, 0, 0, 0);
            acc = __builtin_amdgcn_mfma_f32_16x16x32_bf16(fxh[0], Bc1, acc, 0, 0, 0);
            acc = __builtin_amdgcn_mfma_f32_16x16x32_bf16(fxh[1], Bc3, acc, 0, 0, 0);
            #pragma unroll
            for (int g = 0; g < 4; ++g) {
                float s = acc[g];
                bool cand = (s <= v1r[g] + MARGIN);
                cmask[g] |= cand ? (1ull << tc) : 0ull;
                v1r[g] = fminf(v1r[g], s);
            }
            Bc0 = Bn0; Bc1 = Bn1; Bc2 = Bn2; Bc3 = Bn3;
        }

        // exact evaluation of candidates only (output-mapping: row = q*4+g)
        #pragma unroll
        for (int g = 0; g < 4; ++g) {
            const int slot = g0 + q * 4 + g;          // uniform across ln15 group
            if (slot < nflag) {
                const int token = flag_s[slot];
                const float* xrow = emb + (size_t)(tok0 + token) * EMB + m * SDIM;
                unsigned long long msk = cmask[g];
                const float x2v = np_sq64(xrow);
                float bv = 3.4e38f; int bk = CBK;
                while (msk) {
                    const int tc = __builtin_ctzll(msk);
                    msk &= msk - 1;                   // ascending tc -> ascending k
                    const int k = tc * 16 + ln15;
                    const float* crow = cb + ((size_t)m * CBK + k) * SDIM;
                    float acc = 0.f;
                    #pragma unroll
                    for (int i = 0; i < 16; ++i) {
                        float4 c4 = *(const float4*)(crow + 4 * i);
                        float4 x4 = *(const float4*)(xrow + 4 * i);
                        acc = __fmaf_rn(x4.x, c4.x, acc);
                        acc = __fmaf_rn(x4.y, c4.y, acc);
                        acc = __fmaf_rn(x4.z, c4.z, acc);
                        acc = __fmaf_rn(x4.w, c4.w, acc);
                    }
                    const float dist = fadd(fsub(x2v, fmul(2.f, acc)), C2s[k]);
                    if (dist < bv) { bv = dist; bk = k; }   // strict < keeps smallest k
                }
                // (val,k)-lexicographic min across the 16 lanes of this q-group
                #pragma unroll
                for (int mask = 1; mask < 16; mask <<= 1) {
                    float ov = __shfl_xor(bv, mask);
                    int   ok = __shfl_xor(bk, mask);
                    if (ov < bv || (ov == bv && ok < bk)) { bv = ov; bk = ok; }
                }
                if (ln15 == 0) {
                    bestk_s[token] = bk;
                    iws[(size_t)m * NTOK + tok0 + token] = (float)bk;
                }
            }
        }
    }
    __syncthreads();

    // ---- gather winning codewords ----
    {
        const int tok = t >> 1, d0 = (t & 1) * 32;
        const int bk  = bestk_s[tok];
        const float* src = cb + ((size_t)m * CBK + bk) * SDIM + d0;
        float* dst = qout + (size_t)(tok0 + tok) * EMB + m * SDIM + d0;
        #pragma unroll
        for (int i = 0; i < 8; ++i)
            *(float4*)(dst + 4 * i) = *(const float4*)(src + 4 * i);
    }
}

extern "C" void kernel_launch(void* const* d_in, const int* in_sizes, int n_in,
                              void* d_out, int out_size, void* d_ws, size_t ws_size,
                              hipStream_t stream) {
    const float* emb = (const float*)d_in[0];   // [8,2048,1024] f32
    const float* cb  = (const float*)d_in[1];   // [16,1024,64] f32
    float* qout = (float*)d_out;                              // [N, EMB] f32
    float* iout = (float*)d_out + (size_t)NTOK * EMB;         // [N, 16] as f32

    unsigned short* bpack = (unsigned short*)d_ws;            // 4 MB
    float* c2g = (float*)((char*)d_ws + 4u * 1024u * 1024u);  // 64 KB
    float* iws = (float*)((char*)d_ws + 4u * 1024u * 1024u + 64u * 1024u); // 1 MB

    prep_kernel<<<dim3(32, 16), 256, 0, stream>>>(cb, bpack, c2g);
    pq_mfma_kernel<<<dim3(NTOK / TOKB * NSUB), 256, 0, stream>>>(
        emb, cb, bpack, c2g, qout, iws);
    idx_transpose_kernel<<<dim3(NTOK / 256), 256, 0, stream>>>(iws, iout);
}